// Round 10
// baseline (93.133 us; speedup 1.0000x reference)
//
#include <hip/hip_runtime.h>

#define NTYPES 50
#define NCATS  20
#define EDIM   64
#define BATCH  4
#define SEQL   256

// Blocks: 512 LL (b, pair{pr, 255-pr}) + 200 IT (b,t) + 4 IC (b) + 1 I0
#define LL_BLOCKS 512
#define IT_BLOCKS 200
#define IC_BLOCKS 4
#define TOTAL_BLOCKS 717
#define NTHREADS 512
#define NWAVE    8

// ws float layout, every slot/counter on its own 128B (32-float) line:
//   value slot (target, g) at ws[(target*16+g)*32]; targets: 0=ll, 1..4=int_b, 5=I0
//   sub-counter g at ws[(96+g)*32]; top counter at ws[112*32]
#define SLOT(tgt, g) (((tgt) * 16 + (g)) * 32)
#define SUBC(g)      ((96 + (g)) * 32)
#define TOPC         (112 * 32)
#define WS_ZERO_FLOATS (112 * 32 + 1)

// Precomputed coefficient tables (beyond the zeroed region, 256KB-aligned):
//   CRt[(k*NTYPES+t)*EDIM+e] = {te*A*f, te*P*f}   (160000 float2, 1.28 MB)
//   CRc[(kc*NCATS+c)*EDIM+e] = {ce*Bm*g, ce*Q*g}  (25600  float2, 0.20 MB)
#define TBL_T_OFF 65536
#define NT_ELEMS  (NTYPES * NTYPES * EDIM)
#define NC_ELEMS  (NCATS * NCATS * EDIM)
#define TBL_C_OFF (TBL_T_OFF + 2 * NT_ELEMS)
#define TBL_BLOCKS ((NT_ELEMS + NC_ELEMS + 255) / 256)   // 726

__device__ __forceinline__ float softplusf(float x) {
    return (x > 0.f) ? x + log1pf(__expf(-x)) : log1pf(__expf(x));
}

__device__ __forceinline__ float waveReduceSum(float v) {
    #pragma unroll
    for (int off = 32; off > 0; off >>= 1) v += __shfl_down(v, off, 64);
    return v;
}

// Event-independent coefficient fusion: C=te*A*f, R=te*P*f keyed (k,tgt,e).
// A/P (and Bm/Q) have layout [K][TGT][E], so element index i maps 1:1.
// The last block (TBL_BLOCKS) zeros the slot/counter region (no memset dispatch).
__global__ __launch_bounds__(256) void build_tables(
        const float* __restrict__ type_emb,
        const float* __restrict__ cat_emb,
        const float* __restrict__ A,
        const float* __restrict__ P,
        const float* __restrict__ Bm,
        const float* __restrict__ Q,
        float2* __restrict__ CRt,
        float2* __restrict__ CRc,
        float* __restrict__ ws) {
    if (blockIdx.x == TBL_BLOCKS) {
        for (int j = threadIdx.x; j < WS_ZERO_FLOATS; j += 256) ws[j] = 0.f;
        return;
    }
    const int i = blockIdx.x * 256 + threadIdx.x;
    if (i < NT_ELEMS) {
        const int e = i & 63, kt = i >> 6;
        const int t = kt % NTYPES, k = kt / NTYPES;
        const float te = type_emb[t * EDIM + e];
        const float f  = type_emb[k * EDIM + e];
        CRt[i] = make_float2(te * A[i] * f, te * P[i] * f);
    } else if (i < NT_ELEMS + NC_ELEMS) {
        const int j = i - NT_ELEMS;
        const int e = j & 63, kc = j >> 6;
        const int c = kc % NCATS, k2 = kc / NCATS;
        const float ce = cat_emb[c * EDIM + e];
        const float g  = cat_emb[k2 * EDIM + e];
        CRc[j] = make_float2(ce * Bm[j] * g, ce * Q[j] * g);
    }
}

// 8 waves/block (5.6 waves/SIMD grid-wide) for latency hiding; sources striped
// s ≡ wave (mod 8). Block count / completion machinery identical to R9.
__global__ __launch_bounds__(NTHREADS) void hawkes_fused(
        const float* __restrict__ times,
        const int*   __restrict__ types,
        const int*   __restrict__ cats,
        const int*   __restrict__ Tp,
        const float* __restrict__ type_emb,
        const float* __restrict__ cat_emb,
        const float* __restrict__ amat,
        const float* __restrict__ bmat,
        const float2* __restrict__ CRt,
        const float2* __restrict__ CRc,
        float* __restrict__ ws,
        float* __restrict__ out) {
    const int blk  = blockIdx.x;
    const int tid  = threadIdx.x;
    const int lane = tid & 63;
    const int wave = tid >> 6;
    const int g    = blk & 15;

    __shared__ float tsh[SEQL];
    __shared__ int   ysh[SEQL];
    __shared__ int   csh[SEQL];
    __shared__ float red1[NWAVE], red2[NWAVE];
    __shared__ float sn[NWAVE][EDIM];
    __shared__ float fin[96];
    __shared__ int   finflag;

    if (blk < LL_BLOCKS) {
        // ---- two events per block: i1 = pr (0..127), i2 = 255-pr (128..255) ----
        const int b  = blk >> 7;
        const int pr = blk & 127;
        const int i1 = pr, i2 = 255 - pr;
        const int base = b * SEQL;

        // stage this sequence once: inner loop reads become LDS broadcasts
        if (tid < SEQL) {
            tsh[tid] = times[base + tid];
            ysh[tid] = types[base + tid];
            csh[tid] = cats[base + tid];
        }
        __syncthreads();

        const int t1 = ysh[i1], t2 = ysh[i2];
        const int c2 = csh[i2 - 1];
        const int c1 = (i1 > 0) ? csh[i1 - 1] : 0;
        const float ti1 = tsh[i1], ti2 = tsh[i2];
        const int tb1 = t1 * EDIM + lane, tb2 = t2 * EDIM + lane;
        const int cb1 = c1 * EDIM + lane, cb2 = c2 * EDIM + lane;

        float acc1 = 0.f, acc2 = 0.f;
        // sources s ≡ wave (mod 8); s < i1 feeds both events, s in [i1,i2) only ev2
        #pragma unroll 4
        for (int s = wave; s < i1; s += NWAVE) {
            const int   k  = ysh[s];
            const int   cs = csh[s];
            const float ts = tsh[s];
            const float2 t1v = CRt[k  * (NTYPES * EDIM) + tb1];
            const float2 t2v = CRt[k  * (NTYPES * EDIM) + tb2];
            const float2 c1v = CRc[cs * (NCATS  * EDIM) + cb1];
            const float2 c2v = CRc[cs * (NCATS  * EDIM) + cb2];
            const float td1 = ti1 - ts, td2 = ti2 - ts;
            acc1 += t1v.x * __expf(-t1v.y * td1) + c1v.x * __expf(-c1v.y * td1);
            acc2 += t2v.x * __expf(-t2v.y * td2) + c2v.x * __expf(-c2v.y * td2);
        }
        const int n1 = (i1 > wave) ? ((i1 - wave + NWAVE - 1) / NWAVE) : 0;
        #pragma unroll 4
        for (int s = wave + NWAVE * n1; s < i2; s += NWAVE) {
            const int   k  = ysh[s];
            const int   cs = csh[s];
            const float ts = tsh[s];
            const float2 t2v = CRt[k  * (NTYPES * EDIM) + tb2];
            const float2 c2v = CRc[cs * (NCATS  * EDIM) + cb2];
            const float td2 = ti2 - ts;
            acc2 += t2v.x * __expf(-t2v.y * td2) + c2v.x * __expf(-c2v.y * td2);
        }
        if (wave == 0) {
            const float te1 = type_emb[t1 * EDIM + lane];
            if (i1 == 0) acc1 += softplusf(te1 * amat[t1 * EDIM + lane]);
            else         acc1 += te1 * (amat[t1 * EDIM + lane] + bmat[c1 * EDIM + lane]);
        } else if (wave == 1) {
            const float te2 = type_emb[t2 * EDIM + lane];
            acc2 += te2 * (amat[t2 * EDIM + lane] + bmat[c2 * EDIM + lane]);
        }
        const float r1 = waveReduceSum(acc1);
        const float r2 = waveReduceSum(acc2);
        if (lane == 0) { red1[wave] = r1; red2[wave] = r2; }
        __syncthreads();
        if (tid == 0) {
            float lam1 = 0.f, lam2 = 0.f;
            #pragma unroll
            for (int u = 0; u < NWAVE; ++u) { lam1 += red1[u]; lam2 += red2[u]; }
            atomicAdd(&ws[SLOT(0, g)], logf(lam1 + 1e-16f) + lam1
                                     + logf(lam2 + 1e-16f) + lam2);
        }
    } else if (blk < LL_BLOCKS + IT_BLOCKS) {
        // ---- horizon integral, type channel, (b, t) ----
        const int bt = blk - LL_BLOCKS;
        const int b = bt / NTYPES, t = bt % NTYPES;
        const int base = b * SEQL;
        const float Tf = (float)Tp[0];
        if (tid < SEQL) {
            tsh[tid] = times[base + tid];
            ysh[tid] = types[base + tid];
        }
        __syncthreads();
        const int tb = t * EDIM + lane;
        float acc = 0.f;
        #pragma unroll 4
        for (int s = wave; s < SEQL; s += NWAVE) {
            const int   k  = ysh[s];
            const float td = Tf - tsh[s];
            const float2 v = CRt[k * (NTYPES * EDIM) + tb];
            acc += v.x * __expf(-v.y * td);
        }
        const float r = waveReduceSum(acc);
        if (lane == 0) red1[wave] = r;
        __syncthreads();
        if (tid == 0) {
            float sum = 0.f;
            #pragma unroll
            for (int u = 0; u < NWAVE; ++u) sum += red1[u];
            atomicAdd(&ws[SLOT(1 + b, g)], sum);
        }
    } else if (blk < LL_BLOCKS + IT_BLOCKS + IC_BLOCKS) {
        // ---- horizon integral, category + base, per b ----
        const int b = blk - LL_BLOCKS - IT_BLOCKS;
        const int base = b * SEQL;
        const float Tf = (float)Tp[0];
        if (tid < SEQL) {
            tsh[tid] = times[base + tid];
            csh[tid] = cats[base + tid];
        }
        __syncthreads();
        const int lc = csh[SEQL - 1];
        const int cb = lc * EDIM + lane;
        float nacc = 0.f;
        #pragma unroll 4
        for (int s = wave; s < SEQL; s += NWAVE) {
            const int   cs = csh[s];
            const float td = Tf - tsh[s];
            const float2 v = CRc[cs * (NCATS * EDIM) + cb];
            nacc += v.x * __expf(-v.y * td);
        }
        sn[wave][lane] = nacc;
        __syncthreads();
        if (wave == 0) {
            float n_e = 0.f;
            #pragma unroll
            for (int u = 0; u < NWAVE; ++u) n_e += sn[u][lane];
            float TA = 0.f, TS = 0.f;
            for (int t = 0; t < NTYPES; ++t) {
                const float tv = type_emb[t * EDIM + lane];
                TA += tv * amat[t * EDIM + lane];
                TS += tv;
            }
            float term = TA + (bmat[lc * EDIM + lane] + n_e) * TS;
            term = waveReduceSum(term);
            if (lane == 0) atomicAdd(&ws[SLOT(1 + b, g)], term);
        }
    } else {
        // ---- I0 ----
        float acc = 0.f;
        for (int t = wave; t < NTYPES; t += NWAVE)
            acc += softplusf(type_emb[t * EDIM + lane] * amat[t * EDIM + lane]);
        const float r = waveReduceSum(acc);
        if (lane == 0) red1[wave] = r;
        __syncthreads();
        if (tid == 0) {
            float sum = 0.f;
            #pragma unroll
            for (int u = 0; u < NWAVE; ++u) sum += red1[u];
            atomicAdd(&ws[SLOT(5, g)], sum);
        }
    }

    // ---- hierarchical completion; atomics-only coherence ----
    if (tid == 0) {
        finflag = 0;
        __asm__ __volatile__("s_waitcnt vmcnt(0)" ::: "memory");
        const unsigned cnt_g = (unsigned)((TOTAL_BLOCKS + 15 - g) >> 4);
        unsigned old = atomicAdd((unsigned int*)&ws[SUBC(g)], 1u);
        if (old == cnt_g - 1u) {
            unsigned o2 = atomicAdd((unsigned int*)&ws[TOPC], 1u);
            if (o2 == 15u) finflag = 1;
        }
    }
    __syncthreads();
    if (finflag) {
        if (tid < 96) fin[tid] = atomicAdd(&ws[tid * 32], 0.f);
        __syncthreads();
        if (tid == 0) {
            float ll = 0.f, i0 = 0.f;
            for (int j = 0; j < 16; ++j) { ll += fin[j]; i0 += fin[80 + j]; }
            const float Tf = (float)Tp[0];
            float tot = 0.f;
            for (int b2 = 0; b2 < BATCH; ++b2) {
                float ib = 0.f;
                for (int j = 0; j < 16; ++j) ib += fin[(1 + b2) * 16 + j];
                tot += ib * (Tf - times[b2 * SEQL + SEQL - 1]) + i0 * times[b2 * SEQL];
            }
            out[0] = -(ll - tot);
        }
    }
}

extern "C" void kernel_launch(void* const* d_in, const int* in_sizes, int n_in,
                              void* d_out, int out_size, void* d_ws, size_t ws_size,
                              hipStream_t stream) {
    const float* times    = (const float*)d_in[0];
    const int*   types    = (const int*)  d_in[1];
    const int*   cats     = (const int*)  d_in[2];
    const int*   Tp       = (const int*)  d_in[3];
    const float* type_emb = (const float*)d_in[4];
    const float* cat_emb  = (const float*)d_in[5];
    const float* amat     = (const float*)d_in[6];
    const float* bmat     = (const float*)d_in[7];
    const float* A        = (const float*)d_in[8];
    const float* P        = (const float*)d_in[9];
    const float* Bm       = (const float*)d_in[10];
    const float* Q        = (const float*)d_in[11];
    float* out = (float*)d_out;
    float* ws  = (float*)d_ws;

    float2* CRt = (float2*)(ws + TBL_T_OFF);
    float2* CRc = (float2*)(ws + TBL_C_OFF);

    // 2 dispatches total: build_tables (+ws zeroing in its extra block), main.
    build_tables<<<TBL_BLOCKS + 1, 256, 0, stream>>>(type_emb, cat_emb,
                                                     A, P, Bm, Q, CRt, CRc, ws);

    hawkes_fused<<<TOTAL_BLOCKS, NTHREADS, 0, stream>>>(times, types, cats, Tp,
                                                        type_emb, cat_emb, amat, bmat,
                                                        CRt, CRc, ws, out);
}